// Round 9
// baseline (403.486 us; speedup 1.0000x reference)
//
#include <hip/hip_runtime.h>

#define HW (512 * 512)
#define QP 260   // pitch (floats): >=256, %32==4 -> staggered banks for row-strided reads
#define WN 12288 // 192*64

typedef __bf16 bf16;
typedef __attribute__((ext_vector_type(8))) __bf16 bf16x8;
typedef __attribute__((ext_vector_type(4))) float f32x4;

__device__ __forceinline__ void cvt_split(float f, bf16& h, bf16& l) {
    h = (bf16)f;
    l = (bf16)(f - (float)h);
}

// Tiny precompute: W -> bf16 hi/lo planes in d_ws (48 KB, L2-resident).
__global__ __launch_bounds__(256) void wcvt_kernel(
    const float* __restrict__ w, bf16* __restrict__ wh, bf16* __restrict__ wl)
{
    const int i = blockIdx.x * 256 + threadIdx.x;
    if (i < WN) {
        bf16 h, l;
        cvt_split(w[i], h, l);
        wh[i] = h;
        wl[i] = l;
    }
}

// Occupancy history: (256,2) -> natural 84V+32A=116 regs but only ~2.4 blocks/CU resident
// (30%). (256,4) caps the allocator at 128 regs/wave: 116 fits -> same codegen, and 4
// blocks/CU become resident. R5's (256,4) failure was a ~152-reg structure under the same
// cap -> spill; this body is the first that fits. Tripwire: FETCH/WRITE must stay exactly
// 264/262 MB — any inflation means the cap bit and we revert to (256,2).
__global__ __launch_bounds__(256, 4) void lwmsa_kernel(
    const float* __restrict__ x,
    const bf16* __restrict__ wh,
    const bf16* __restrict__ wl,
    float* __restrict__ out)
{
    const int win  = blockIdx.x;       // 0..4095
    const int b    = win >> 10;
    const int wrow = (win >> 5) & 31;
    const int wcol = win & 31;
    const int n    = threadIdx.x;      // 0..255 = pixel in window
    const int lane = n & 63;
    const int wvid = n >> 6;           // wave 0..3
    const int c16  = lane & 15;
    const int q4   = lane >> 4;

    const int base = b * (64 * HW) + (wrow * 16 + (n >> 4)) * 512 + wcol * 16 + (n & 15);
    const int xwin = b * (64 * HW) + (wrow * 16) * 512 + wcol * 16;

    __shared__ float qk[24 * QP];      // current head: q rows 0-7, k 8-15, v 16-23
    __shared__ float kvp[4 * 64];
    __shared__ float kv_s[64];
    __shared__ float tp[2][4];         // parity-buffered k-sum partials

    // ---- A-fragments (X), hi/lo, global -> registers, persistent across all heads ----
    bf16x8 ah[2][4], al[2][4];
    #pragma unroll
    for (int ks = 0; ks < 2; ++ks)
        #pragma unroll
        for (int mt = 0; mt < 4; ++mt) {
            const int row = wvid * 4 + mt;
            const float* xp = x + xwin + row * 512 + c16 + (ks * 32 + q4 * 8) * HW;
            #pragma unroll
            for (int j = 0; j < 8; ++j) {
                bf16 h, l;
                cvt_split(xp[j * HW], h, l);
                ah[ks][mt][j] = h;
                al[ks][mt][j] = l;
            }
        }

    // ---- per-head MFMA + stage: 24 rows (q0-7,k8-15,v16-23) of head hh ----
    auto mfma_stage = [&](int hh) {
        f32x4 acc[4][2];
        #pragma unroll
        for (int mt = 0; mt < 4; ++mt)
            #pragma unroll
            for (int nt = 0; nt < 2; ++nt)
                acc[mt][nt] = (f32x4){0.f, 0.f, 0.f, 0.f};

        #pragma unroll
        for (int ks = 0; ks < 2; ++ks) {
            #pragma unroll
            for (int nt = 0; nt < 2; ++nt) {
                const int ml   = nt * 16 + c16;                 // 0..31; valid < 24
                const int grow = (ml < 24) ? ((ml >> 3) * 64 + hh * 8 + (ml & 7))
                                           : (hh * 8);          // in-bounds dummy
                const int off  = grow * 64 + ks * 32 + q4 * 8;
                const bf16x8 bh = *(const bf16x8*)&wh[off];
                const bf16x8 bl = *(const bf16x8*)&wl[off];
                #pragma unroll
                for (int mt = 0; mt < 4; ++mt) {
                    acc[mt][nt] = __builtin_amdgcn_mfma_f32_16x16x32_bf16(ah[ks][mt], bh, acc[mt][nt], 0, 0, 0);
                    acc[mt][nt] = __builtin_amdgcn_mfma_f32_16x16x32_bf16(al[ks][mt], bh, acc[mt][nt], 0, 0, 0);
                    acc[mt][nt] = __builtin_amdgcn_mfma_f32_16x16x32_bf16(ah[ks][mt], bl, acc[mt][nt], 0, 0, 0);
                }
            }
        }

        // D: lane holds qkv-row ml=nt*16+c16 at px=(wvid*4+mt)*16+q4*4+reg
        #pragma unroll
        for (int nt = 0; nt < 2; ++nt) {
            const int ml = nt * 16 + c16;
            if (ml < 24) {
                #pragma unroll
                for (int mt = 0; mt < 4; ++mt) {
                    const int px = (wvid * 4 + mt) * 16 + q4 * 4;
                    *(float4*)&qk[ml * QP + px] = *(float4*)&acc[mt][nt];
                }
            }
        }
    };

    float feat[8];
    #pragma unroll
    for (int d = 0; d < 8; ++d) feat[d] = 0.f;

    mfma_stage(0);
    __syncthreads();  // S_init: head 0 projections visible

    for (int h = 0; h < 8; ++h) {
        // ---- phase A: proj read + feat, elu1, row sums; write kf/av back (own column) ----
        float qf[8];
        float Sq = 0.f, tpart = 0.f;
        #pragma unroll
        for (int d = 0; d < 8; ++d) {
            const float aq = qk[d * QP + n]        + feat[d];
            const float ak = qk[(8 + d) * QP + n]  + feat[d];
            const float av = qk[(16 + d) * QP + n] + feat[d];
            qf[d] = aq > 0.f ? aq + 1.f : __expf(aq);
            const float kf = ak > 0.f ? ak + 1.f : __expf(ak);
            Sq    += qf[d];
            tpart += kf;
            qk[(8 + d) * QP + n]  = kf;
            qk[(16 + d) * QP + n] = av;
        }

        #pragma unroll
        for (int off = 1; off < 64; off <<= 1)
            tpart += __shfl_xor(tpart, off, 64);
        if (lane == 0) tp[h & 1][wvid] = tpart;

        // wave-internal handoff: kv phase below reads ONLY this wave's 64 columns.
        asm volatile("s_waitcnt lgkmcnt(0)" ::: "memory");

        // ---- phase B: kv partials: (d'=lane>>3, c=lane&7) over this wave's 64 px ----
        {
            const float4* kr = (const float4*)(qk + (8 + (lane >> 3)) * QP + wvid * 64);
            const float4* vr = (const float4*)(qk + (16 + (lane & 7)) * QP + wvid * 64);
            float s0 = 0.f, s1 = 0.f, s2 = 0.f, s3 = 0.f;
            #pragma unroll
            for (int j = 0; j < 16; ++j) {
                const float4 kk = kr[j];
                const float4 vv = vr[j];
                s0 = fmaf(kk.x, vv.x, s0);
                s1 = fmaf(kk.y, vv.y, s1);
                s2 = fmaf(kk.z, vv.z, s2);
                s3 = fmaf(kk.w, vv.w, s3);
            }
            kvp[wvid * 64 + lane] = (s0 + s1) + (s2 + s3);
        }

        __syncthreads();  // S3: kvp + tp visible; qk k/v rows dead -> restage allowed

        // ---- phase C: final kv reduce (n<64) overlapped with next head's MFMA+stage ----
        if (n < 64)
            kv_s[n] = (kvp[n] + kvp[64 + n]) + (kvp[128 + n] + kvp[192 + n]);

        if (h < 7)
            mfma_stage(h + 1);

        __syncthreads();  // S4: kv_s + next head's projections visible

        // ---- phase D: z, feat, out ----
        const float T  = ((tp[h & 1][0] + tp[h & 1][1]) + (tp[h & 1][2] + tp[h & 1][3])) + 8.0f * 1e-6f;
        const float zi = 1.0f / (Sq * T);

        float ft[8];
        #pragma unroll
        for (int d = 0; d < 8; ++d) ft[d] = 0.f;
        #pragma unroll
        for (int d = 0; d < 8; ++d) {
            const float qd = qf[d];
            const float4 a  = ((const float4*)(kv_s + d * 8))[0];
            const float4 bb = ((const float4*)(kv_s + d * 8))[1];
            ft[0] = fmaf(qd, a.x,  ft[0]);
            ft[1] = fmaf(qd, a.y,  ft[1]);
            ft[2] = fmaf(qd, a.z,  ft[2]);
            ft[3] = fmaf(qd, a.w,  ft[3]);
            ft[4] = fmaf(qd, bb.x, ft[4]);
            ft[5] = fmaf(qd, bb.y, ft[5]);
            ft[6] = fmaf(qd, bb.z, ft[6]);
            ft[7] = fmaf(qd, bb.w, ft[7]);
        }
        #pragma unroll
        for (int d = 0; d < 8; ++d) {
            feat[d] = ft[d] * zi;
            out[base + (h * 8 + d) * HW] = feat[d];
        }
    }
}

extern "C" void kernel_launch(void* const* d_in, const int* in_sizes, int n_in,
                              void* d_out, int out_size, void* d_ws, size_t ws_size,
                              hipStream_t stream) {
    const float* x  = (const float*)d_in[0];
    const float* w  = (const float*)d_in[1];
    float* out      = (float*)d_out;
    bf16* wh = (bf16*)d_ws;
    bf16* wl = wh + WN;
    wcvt_kernel<<<dim3((WN + 255) / 256), dim3(256), 0, stream>>>(w, wh, wl);
    lwmsa_kernel<<<dim3(4096), dim3(256), 0, stream>>>(x, wh, wl, out);
}

// Round 10
// 256.583 us; speedup vs baseline: 1.5725x; 1.5725x over previous
//
#include <hip/hip_runtime.h>

#define HW (512 * 512)
#define QP 260   // pitch (floats): >=256, %32==4 -> staggered banks for row-strided reads
#define WN 12288 // 192*64

typedef __bf16 bf16;
typedef __attribute__((ext_vector_type(8))) __bf16 bf16x8;
typedef __attribute__((ext_vector_type(4))) float f32x4;

__device__ __forceinline__ void cvt_split(float f, bf16& h, bf16& l) {
    h = (bf16)f;
    l = (bf16)(f - (float)h);
}

// Tiny precompute: W -> bf16 hi/lo planes in d_ws (48 KB, L2-resident).
__global__ __launch_bounds__(256) void wcvt_kernel(
    const float* __restrict__ w, bf16* __restrict__ wh, bf16* __restrict__ wl)
{
    const int i = blockIdx.x * 256 + threadIdx.x;
    if (i < WN) {
        bf16 h, l;
        cvt_split(w[i], h, l);
        wh[i] = h;
        wl[i] = l;
    }
}

// TWO windows per block (same row, adjacent cols): every barrier segment carries two
// independent instruction streams -> stall-filling via ILP, not occupancy.
// Launch bounds (256,2): budget 256 regs/wave; natural ~200V+32A fits -> NO cap-induced
// spill (R4/R5/R9 proved any cap below natural demand => FETCH/WRITE inflation).
// Tripwire: FETCH ~264 MB, WRITE = 262 MB exactly.
__global__ __launch_bounds__(256, 2) void lwmsa_kernel(
    const float* __restrict__ x,
    const bf16* __restrict__ wh,
    const bf16* __restrict__ wl,
    float* __restrict__ out)
{
    const int blk  = blockIdx.x;       // 0..2047
    const int b    = blk >> 9;
    const int wrow = (blk >> 4) & 31;
    const int wp   = blk & 15;         // col pair: wcol = 2*wp + w
    const int n    = threadIdx.x;      // 0..255 = pixel in window
    const int lane = n & 63;
    const int wvid = n >> 6;           // wave 0..3
    const int c16  = lane & 15;
    const int q4   = lane >> 4;

    __shared__ float qk[2][24 * QP];   // per window: q rows 0-7, k 8-15, v 16-23
    __shared__ float kvp[2][4 * 64];
    __shared__ float kv_s[2][64];
    __shared__ float tp[2][2][4];      // [win][parity][wave]

    int base[2], xwin[2];
    #pragma unroll
    for (int w = 0; w < 2; ++w) {
        const int wcol = wp * 2 + w;
        base[w] = b * (64 * HW) + (wrow * 16 + (n >> 4)) * 512 + wcol * 16 + (n & 15);
        xwin[w] = b * (64 * HW) + (wrow * 16) * 512 + wcol * 16;
    }

    // ---- A-fragments (X) for both windows, hi/lo, global -> registers ----
    bf16x8 ah[2][2][4], al[2][2][4];   // [win][ks][mt]
    #pragma unroll
    for (int w = 0; w < 2; ++w)
        #pragma unroll
        for (int ks = 0; ks < 2; ++ks)
            #pragma unroll
            for (int mt = 0; mt < 4; ++mt) {
                const int row = wvid * 4 + mt;
                const float* xp = x + xwin[w] + row * 512 + c16 + (ks * 32 + q4 * 8) * HW;
                #pragma unroll
                for (int j = 0; j < 8; ++j) {
                    bf16 h, l;
                    cvt_split(xp[j * HW], h, l);
                    ah[w][ks][mt][j] = h;
                    al[w][ks][mt][j] = l;
                }
            }

    // ---- per-head MFMA + stage into qkb: 24 rows (q0-7,k8-15,v16-23) of head hh ----
    auto mfma_stage = [&](const bf16x8 (&Ah)[2][4], const bf16x8 (&Al)[2][4],
                          float* __restrict__ qkb, int hh) {
        f32x4 acc[4][2];
        #pragma unroll
        for (int mt = 0; mt < 4; ++mt)
            #pragma unroll
            for (int nt = 0; nt < 2; ++nt)
                acc[mt][nt] = (f32x4){0.f, 0.f, 0.f, 0.f};

        #pragma unroll
        for (int ks = 0; ks < 2; ++ks) {
            #pragma unroll
            for (int nt = 0; nt < 2; ++nt) {
                const int ml   = nt * 16 + c16;                 // 0..31; valid < 24
                const int grow = (ml < 24) ? ((ml >> 3) * 64 + hh * 8 + (ml & 7))
                                           : (hh * 8);          // in-bounds dummy
                const int off  = grow * 64 + ks * 32 + q4 * 8;
                const bf16x8 bh = *(const bf16x8*)&wh[off];
                const bf16x8 bl = *(const bf16x8*)&wl[off];
                #pragma unroll
                for (int mt = 0; mt < 4; ++mt) {
                    acc[mt][nt] = __builtin_amdgcn_mfma_f32_16x16x32_bf16(Ah[ks][mt], bh, acc[mt][nt], 0, 0, 0);
                    acc[mt][nt] = __builtin_amdgcn_mfma_f32_16x16x32_bf16(Al[ks][mt], bh, acc[mt][nt], 0, 0, 0);
                    acc[mt][nt] = __builtin_amdgcn_mfma_f32_16x16x32_bf16(Ah[ks][mt], bl, acc[mt][nt], 0, 0, 0);
                }
            }
        }

        // D: lane holds qkv-row ml=nt*16+c16 at px=(wvid*4+mt)*16+q4*4+reg
        #pragma unroll
        for (int nt = 0; nt < 2; ++nt) {
            const int ml = nt * 16 + c16;
            if (ml < 24) {
                #pragma unroll
                for (int mt = 0; mt < 4; ++mt) {
                    const int px = (wvid * 4 + mt) * 16 + q4 * 4;
                    *(float4*)&qkb[ml * QP + px] = *(float4*)&acc[mt][nt];
                }
            }
        }
    };

    float feat[2][8];
    #pragma unroll
    for (int w = 0; w < 2; ++w)
        #pragma unroll
        for (int d = 0; d < 8; ++d) feat[w][d] = 0.f;

    mfma_stage(ah[0], al[0], qk[0], 0);
    mfma_stage(ah[1], al[1], qk[1], 0);
    __syncthreads();  // S_init: head-0 projections of both windows visible

    for (int h = 0; h < 8; ++h) {
        // ---- phase A (x2): proj+feat, elu1, row sums; write kf/av back (own column) ----
        float qf[2][8], Sq[2], tpart[2];
        #pragma unroll
        for (int w = 0; w < 2; ++w) {
            Sq[w] = 0.f; tpart[w] = 0.f;
            #pragma unroll
            for (int d = 0; d < 8; ++d) {
                const float aq = qk[w][d * QP + n]        + feat[w][d];
                const float ak = qk[w][(8 + d) * QP + n]  + feat[w][d];
                const float av = qk[w][(16 + d) * QP + n] + feat[w][d];
                qf[w][d] = aq > 0.f ? aq + 1.f : __expf(aq);
                const float kf = ak > 0.f ? ak + 1.f : __expf(ak);
                Sq[w]    += qf[w][d];
                tpart[w] += kf;
                qk[w][(8 + d) * QP + n]  = kf;
                qk[w][(16 + d) * QP + n] = av;
            }
        }

        #pragma unroll
        for (int off = 1; off < 64; off <<= 1) {
            tpart[0] += __shfl_xor(tpart[0], off, 64);
            tpart[1] += __shfl_xor(tpart[1], off, 64);
        }
        if (lane == 0) {
            tp[0][h & 1][wvid] = tpart[0];
            tp[1][h & 1][wvid] = tpart[1];
        }

        // wave-internal handoff: phase B reads only this wave's 64 columns (verified R8)
        asm volatile("s_waitcnt lgkmcnt(0)" ::: "memory");

        // ---- phase B (x2): kv partials over this wave's 64 px ----
        #pragma unroll
        for (int w = 0; w < 2; ++w) {
            const float4* kr = (const float4*)(qk[w] + (8 + (lane >> 3)) * QP + wvid * 64);
            const float4* vr = (const float4*)(qk[w] + (16 + (lane & 7)) * QP + wvid * 64);
            float s0 = 0.f, s1 = 0.f, s2 = 0.f, s3 = 0.f;
            #pragma unroll
            for (int j = 0; j < 16; ++j) {
                const float4 kk = kr[j];
                const float4 vv = vr[j];
                s0 = fmaf(kk.x, vv.x, s0);
                s1 = fmaf(kk.y, vv.y, s1);
                s2 = fmaf(kk.z, vv.z, s2);
                s3 = fmaf(kk.w, vv.w, s3);
            }
            kvp[w][wvid * 64 + lane] = (s0 + s1) + (s2 + s3);
        }

        __syncthreads();  // S3: kvp + tp visible; qk buffers dead -> restage allowed

        // ---- phase C: final kv reduce (128 lanes) overlapped with next head's MFMA ----
        if (n < 64) {
            kv_s[0][n] = (kvp[0][n] + kvp[0][64 + n]) + (kvp[0][128 + n] + kvp[0][192 + n]);
        } else if (n < 128) {
            const int m = n - 64;
            kv_s[1][m] = (kvp[1][m] + kvp[1][64 + m]) + (kvp[1][128 + m] + kvp[1][192 + m]);
        }

        if (h < 7) {
            mfma_stage(ah[0], al[0], qk[0], h + 1);
            mfma_stage(ah[1], al[1], qk[1], h + 1);
        }

        __syncthreads();  // S4: kv_s + next head's projections visible

        // ---- phase D (x2): z, feat, out ----
        #pragma unroll
        for (int w = 0; w < 2; ++w) {
            const float T  = ((tp[w][h & 1][0] + tp[w][h & 1][1]) +
                              (tp[w][h & 1][2] + tp[w][h & 1][3])) + 8.0f * 1e-6f;
            const float zi = 1.0f / (Sq[w] * T);

            float ft[8];
            #pragma unroll
            for (int d = 0; d < 8; ++d) ft[d] = 0.f;
            #pragma unroll
            for (int d = 0; d < 8; ++d) {
                const float qd = qf[w][d];
                const float4 a  = ((const float4*)(kv_s[w] + d * 8))[0];
                const float4 bb = ((const float4*)(kv_s[w] + d * 8))[1];
                ft[0] = fmaf(qd, a.x,  ft[0]);
                ft[1] = fmaf(qd, a.y,  ft[1]);
                ft[2] = fmaf(qd, a.z,  ft[2]);
                ft[3] = fmaf(qd, a.w,  ft[3]);
                ft[4] = fmaf(qd, bb.x, ft[4]);
                ft[5] = fmaf(qd, bb.y, ft[5]);
                ft[6] = fmaf(qd, bb.z, ft[6]);
                ft[7] = fmaf(qd, bb.w, ft[7]);
            }
            #pragma unroll
            for (int d = 0; d < 8; ++d) {
                feat[w][d] = ft[d] * zi;
                out[base[w] + (h * 8 + d) * HW] = feat[w][d];
            }
        }
    }
}

extern "C" void kernel_launch(void* const* d_in, const int* in_sizes, int n_in,
                              void* d_out, int out_size, void* d_ws, size_t ws_size,
                              hipStream_t stream) {
    const float* x  = (const float*)d_in[0];
    const float* w  = (const float*)d_in[1];
    float* out      = (float*)d_out;
    bf16* wh = (bf16*)d_ws;
    bf16* wl = wh + WN;
    wcvt_kernel<<<dim3((WN + 255) / 256), dim3(256), 0, stream>>>(w, wh, wl);
    lwmsa_kernel<<<dim3(2048), dim3(256), 0, stream>>>(x, wh, wl, out);
}